// Round 1
// baseline (178.137 us; speedup 1.0000x reference)
//
#include <hip/hip_runtime.h>
#include <stdint.h>
#include <stddef.h>

// Problem constants (match reference setup_inputs)
static constexpr int Bb = 2;      // batch
static constexpr int Mq = 4096;   // queries per batch
static constexpr int Cc = 256;    // channels (GEMM K)
static constexpr int Hh = 64, Ww = 64;
static constexpr int Np = Hh * Ww;     // 4096 pixels (GEMM N)
static constexpr int RAD = 4;
static constexpr int SIDE = 2 * RAD + 1;     // 9
static constexpr int KPL = SIDE * SIDE;      // 81
static constexpr int NLVL = 4;
static constexpr int KTOT = NLVL * KPL;      // 324

// Pyramid layout in workspace (float offsets)
static constexpr size_t L0_OFF = 0;                         // 8192*4096
static constexpr size_t L1_OFF = (size_t)Bb * Mq * 64 * 64; // 33554432
static constexpr size_t L2_OFF = L1_OFF + (size_t)Bb * Mq * 32 * 32;
static constexpr size_t L3_OFF = L2_OFF + (size_t)Bb * Mq * 16 * 16;

typedef float floatx4 __attribute__((ext_vector_type(4)));
typedef short shortx8 __attribute__((ext_vector_type(8)));

union BfPack {
    shortx8 v;
    unsigned short u[8];
};

// fp32 -> bf16 round-to-nearest-even (finite inputs only)
__device__ __forceinline__ unsigned short f2bf(float f) {
    unsigned int x = __float_as_uint(f);
    x += 0x7fffu + ((x >> 16) & 1u);
    return (unsigned short)(x >> 16);
}

// XOR swizzle of the k-group (8 bf16 = 16B) within a 32-elem LDS row:
// spreads ds_read_b128 fragment reads across bank groups (<=2-way conflict).
__device__ __forceinline__ int ksw(int row, int g) {
    return 8 * (g ^ ((row >> 1) & 3));
}

// ---------------------------------------------------------------------------
// corr[b*Mq+m][p] = sum_c fmap1[b][m][c] * fmap2[b][c][p]
// 128x128 tile per block, BK=32, bf16 MFMA 16x16x32, 4 waves, 4x4 tiles/wave.
// ---------------------------------------------------------------------------
__global__ __launch_bounds__(256)
void corr_gemm_kernel(const float* __restrict__ A,   // (Bb*Mq, Cc)
                      const float* __restrict__ B2,  // (Bb, Cc, Np)
                      float* __restrict__ corr)      // (Bb*Mq, Np)
{
    __shared__ unsigned short la[128 * 32];  // A tile, row-major [m][k]
    __shared__ unsigned short lb[128 * 32];  // B tile, n-major  [n][k]

    const int b    = blockIdx.z;
    const int bm0  = blockIdx.y * 128;
    const int bn0  = blockIdx.x * 128;
    const int tid  = threadIdx.x;
    const int lane = tid & 63;
    const int wave = tid >> 6;
    const int lane15 = lane & 15;
    const int quad   = lane >> 4;
    const int wm = (wave >> 1) * 64;
    const int wn = (wave & 1) * 64;

    const float* Abase = A + (size_t)(b * Mq + bm0) * Cc;
    const float* Bbase = B2 + (size_t)b * Cc * Np + bn0;

    floatx4 acc[4][4];
#pragma unroll
    for (int i = 0; i < 4; ++i)
#pragma unroll
        for (int j = 0; j < 4; ++j)
            acc[i][j] = floatx4{0.0f, 0.0f, 0.0f, 0.0f};

    const int a_row = tid >> 2;   // 0..63 (round adds 64)
    const int a_g   = tid & 3;    // k-group 0..3
    const int b_n   = tid & 127;  // 0..127
    const int b_g0  = tid >> 7;   // 0..1 (round adds 2)

    for (int k0 = 0; k0 < Cc; k0 += 32) {
        __syncthreads();
        // ---- stage A tile (fp32 -> bf16), coalesced 32B per lane
#pragma unroll
        for (int r = 0; r < 2; ++r) {
            const int row = a_row + r * 64;
            const float* src = Abase + (size_t)row * Cc + k0 + a_g * 8;
            const float4 v0 = *(const float4*)(src);
            const float4 v1 = *(const float4*)(src + 4);
            BfPack p;
            p.u[0] = f2bf(v0.x); p.u[1] = f2bf(v0.y);
            p.u[2] = f2bf(v0.z); p.u[3] = f2bf(v0.w);
            p.u[4] = f2bf(v1.x); p.u[5] = f2bf(v1.y);
            p.u[6] = f2bf(v1.z); p.u[7] = f2bf(v1.w);
            *(shortx8*)&la[row * 32 + ksw(row, a_g)] = p.v;
        }
        // ---- stage B tile transposed into n-major LDS.
        // Each item: one n, 8 k's (stride Np in global; coalesced across lanes).
#pragma unroll
        for (int r = 0; r < 2; ++r) {
            const int g = b_g0 + r * 2;
            const float* src = Bbase + (size_t)(k0 + g * 8) * Np + b_n;
            BfPack p;
#pragma unroll
            for (int u = 0; u < 8; ++u)
                p.u[u] = f2bf(src[(size_t)u * Np]);
            *(shortx8*)&lb[b_n * 32 + ksw(b_n, g)] = p.v;
        }
        __syncthreads();
        // ---- fragments + MFMA
        // A-frag: lane holds A[m=lane15][k=quad*8+j]; B-frag: B[k=quad*8+j][n=lane15]
        shortx8 af[4], bf[4];
#pragma unroll
        for (int i = 0; i < 4; ++i) {
            const int row = wm + i * 16 + lane15;
            af[i] = *(const shortx8*)&la[row * 32 + ksw(row, quad)];
        }
#pragma unroll
        for (int j = 0; j < 4; ++j) {
            const int nn = wn + j * 16 + lane15;
            bf[j] = *(const shortx8*)&lb[nn * 32 + ksw(nn, quad)];
        }
#pragma unroll
        for (int i = 0; i < 4; ++i)
#pragma unroll
            for (int j = 0; j < 4; ++j)
                acc[i][j] = __builtin_amdgcn_mfma_f32_16x16x32_bf16(
                    af[i], bf[j], acc[i][j], 0, 0, 0);
    }

    // ---- epilogue: C/D layout col=lane&15, row=quad*4+reg (m89/m91 verified)
#pragma unroll
    for (int i = 0; i < 4; ++i) {
#pragma unroll
        for (int j = 0; j < 4; ++j) {
#pragma unroll
            for (int reg = 0; reg < 4; ++reg) {
                const int row = bm0 + wm + i * 16 + quad * 4 + reg;
                const int col = bn0 + wn + j * 16 + lane15;
                corr[(size_t)(b * Mq + row) * Np + col] = acc[i][j][reg];
            }
        }
    }
}

// ---------------------------------------------------------------------------
// 2x2 average pool: src (imgs, 2w, 2w) -> dst (imgs, w, w); lw = log2(w)
// ---------------------------------------------------------------------------
__global__ void pool_kernel(const float* __restrict__ src, float* __restrict__ dst,
                            int lw, int n_total)
{
    const int idx = blockIdx.x * blockDim.x + threadIdx.x;
    if (idx >= n_total) return;
    const int wd  = 1 << lw;
    const int ws2 = wd << 1;
    const int img = idx >> (2 * lw);
    const int rem = idx & ((1 << (2 * lw)) - 1);
    const int y = rem >> lw;
    const int x = rem & (wd - 1);
    const float* s = src + ((size_t)img << (2 * (lw + 1)))
                   + (size_t)(2 * y) * ws2 + 2 * x;
    dst[idx] = 0.25f * (s[0] + s[1] + s[ws2] + s[ws2 + 1]);
}

// ---------------------------------------------------------------------------
// Bilinear lookup over 4 pyramid levels, zeros padding (per-corner validity).
// out layout (B, 324, Mq): gid = (b*324 + k)*Mq + m  (coalesced writes in m).
// Within a block k is uniform -> no divergence on lvl.
// ---------------------------------------------------------------------------
__global__ void sample_kernel(const float* __restrict__ cent, // (Bb*Mq, 2)
                              const float* __restrict__ pyr,
                              float* __restrict__ out)
{
    const int gid = blockIdx.x * blockDim.x + threadIdx.x;
    constexpr int TOT = Bb * KTOT * Mq;
    if (gid >= TOT) return;
    const int m = gid & (Mq - 1);
    const int t = gid >> 12;          // b*324 + k
    const int b = t / KTOT;
    const int k = t - b * KTOT;
    const int lvl = k / KPL;
    const int r   = k - lvl * KPL;
    const int di  = r / SIDE;         // x-offset index
    const int dj  = r - di * SIDE;    // y-offset index

    const size_t lvl_off[4] = {L0_OFF, L1_OFF, L2_OFF, L3_OFF};
    const int w = Ww >> lvl;
    const float scale = 1.0f / (float)(1 << lvl);
    const float* img = pyr + lvl_off[lvl] + (size_t)(b * Mq + m) * (w * w);

    const float cx = cent[(size_t)(b * Mq + m) * 2 + 0] * scale;
    const float cy = cent[(size_t)(b * Mq + m) * 2 + 1] * scale;
    const float x = cx + (float)(di - RAD);
    const float y = cy + (float)(dj - RAD);

    const float x0f = floorf(x), y0f = floorf(y);
    const float wx1 = x - x0f, wx0 = 1.0f - wx1;
    const float wy1 = y - y0f, wy0 = 1.0f - wy1;
    const float fmx = (float)(w - 1);
    const bool vx0 = (x0f >= 0.0f) && (x0f <= fmx);
    const bool vx1 = (x0f + 1.0f >= 0.0f) && (x0f + 1.0f <= fmx);
    const bool vy0 = (y0f >= 0.0f) && (y0f <= fmx);
    const bool vy1 = (y0f + 1.0f >= 0.0f) && (y0f + 1.0f <= fmx);

    const int ix0 = (int)x0f, iy0 = (int)y0f;
    const int ix0c = min(max(ix0, 0), w - 1);
    const int ix1c = min(max(ix0 + 1, 0), w - 1);
    const int iy0c = min(max(iy0, 0), w - 1);
    const int iy1c = min(max(iy0 + 1, 0), w - 1);

    const float g00 = (vx0 && vy0) ? img[iy0c * w + ix0c] : 0.0f;
    const float g10 = (vx1 && vy0) ? img[iy0c * w + ix1c] : 0.0f;
    const float g01 = (vx0 && vy1) ? img[iy1c * w + ix0c] : 0.0f;
    const float g11 = (vx1 && vy1) ? img[iy1c * w + ix1c] : 0.0f;

    out[gid] = wy0 * (wx0 * g00 + wx1 * g10) + wy1 * (wx0 * g01 + wx1 * g11);
}

extern "C" void kernel_launch(void* const* d_in, const int* in_sizes, int n_in,
                              void* d_out, int out_size, void* d_ws, size_t ws_size,
                              hipStream_t stream)
{
    const float* fmap1 = (const float*)d_in[0];   // (Bb, Mq, Cc)
    const float* fmap2 = (const float*)d_in[1];   // (Bb, Cc, Hh, Ww)
    const float* cent  = (const float*)d_in[2];   // (Bb, Mq, 2)
    float* pyr = (float*)d_ws;                    // needs ~178 MB
    float* out = (float*)d_out;

    // 1) correlation volume (level 0)
    dim3 ggrid(Np / 128, Mq / 128, Bb);
    corr_gemm_kernel<<<ggrid, 256, 0, stream>>>(fmap1, fmap2, pyr + L0_OFF);

    // 2) pyramid levels 1..3
    {
        const int n1 = Bb * Mq * 32 * 32;
        pool_kernel<<<(n1 + 255) / 256, 256, 0, stream>>>(pyr + L0_OFF, pyr + L1_OFF, 5, n1);
        const int n2 = Bb * Mq * 16 * 16;
        pool_kernel<<<(n2 + 255) / 256, 256, 0, stream>>>(pyr + L1_OFF, pyr + L2_OFF, 4, n2);
        const int n3 = Bb * Mq * 8 * 8;
        pool_kernel<<<(n3 + 255) / 256, 256, 0, stream>>>(pyr + L2_OFF, pyr + L3_OFF, 3, n3);
    }

    // 3) bilinear lookups -> (B, 324, Mq)
    const int ntot = Bb * KTOT * Mq;
    sample_kernel<<<(ntot + 255) / 256, 256, 0, stream>>>(cent, pyr, out);
}

// Round 2
// 145.256 us; speedup vs baseline: 1.2264x; 1.2264x over previous
//
#include <hip/hip_runtime.h>
#include <stdint.h>
#include <stddef.h>

// Problem constants (match reference setup_inputs)
static constexpr int Bb = 2;      // batch
static constexpr int Mq = 4096;   // queries per batch
static constexpr int Cc = 256;    // channels (GEMM K)
static constexpr int Hh = 64, Ww = 64;
static constexpr int Np = Hh * Ww;     // 4096 pixels (GEMM N)
static constexpr int RAD = 4;
static constexpr int SIDE = 2 * RAD + 1;     // 9
static constexpr int KPL = SIDE * SIDE;      // 81
static constexpr int NLVL = 4;
static constexpr int KTOT = NLVL * KPL;      // 324

typedef float floatx4 __attribute__((ext_vector_type(4)));
typedef short shortx8 __attribute__((ext_vector_type(8)));

union BfPack {
    shortx8 v;
    unsigned short u[8];
};

// fp32 -> bf16 round-to-nearest-even (finite inputs only)
__device__ __forceinline__ unsigned short f2bf(float f) {
    unsigned int x = __float_as_uint(f);
    x += 0x7fffu + ((x >> 16) & 1u);
    return (unsigned short)(x >> 16);
}

// XOR swizzle of the k-group (8 bf16 = 16B) within a 32-elem LDS row
__device__ __forceinline__ int ksw(int row, int g) {
    return 8 * (g ^ ((row >> 1) & 3));
}

// ---------------------------------------------------------------------------
// corr[b*Mq+m][p] = sum_c fmap1[b][m][c] * fmap2[b][c][p]
// 128x128 tile per block, BK=32, bf16 MFMA 16x16x32, 4 waves, 4x4 tiles/wave.
// (unchanged from round 1 — passed, 60 us)
// ---------------------------------------------------------------------------
__global__ __launch_bounds__(256)
void corr_gemm_kernel(const float* __restrict__ A,   // (Bb*Mq, Cc)
                      const float* __restrict__ B2,  // (Bb, Cc, Np)
                      float* __restrict__ corr)      // (Bb*Mq, Np)
{
    __shared__ unsigned short la[128 * 32];  // A tile, row-major [m][k]
    __shared__ unsigned short lb[128 * 32];  // B tile, n-major  [n][k]

    const int b    = blockIdx.z;
    const int bm0  = blockIdx.y * 128;
    const int bn0  = blockIdx.x * 128;
    const int tid  = threadIdx.x;
    const int lane = tid & 63;
    const int wave = tid >> 6;
    const int lane15 = lane & 15;
    const int quad   = lane >> 4;
    const int wm = (wave >> 1) * 64;
    const int wn = (wave & 1) * 64;

    const float* Abase = A + (size_t)(b * Mq + bm0) * Cc;
    const float* Bbase = B2 + (size_t)b * Cc * Np + bn0;

    floatx4 acc[4][4];
#pragma unroll
    for (int i = 0; i < 4; ++i)
#pragma unroll
        for (int j = 0; j < 4; ++j)
            acc[i][j] = floatx4{0.0f, 0.0f, 0.0f, 0.0f};

    const int a_row = tid >> 2;   // 0..63 (round adds 64)
    const int a_g   = tid & 3;    // k-group 0..3
    const int b_n   = tid & 127;  // 0..127
    const int b_g0  = tid >> 7;   // 0..1 (round adds 2)

    for (int k0 = 0; k0 < Cc; k0 += 32) {
        __syncthreads();
#pragma unroll
        for (int r = 0; r < 2; ++r) {
            const int row = a_row + r * 64;
            const float* src = Abase + (size_t)row * Cc + k0 + a_g * 8;
            const float4 v0 = *(const float4*)(src);
            const float4 v1 = *(const float4*)(src + 4);
            BfPack p;
            p.u[0] = f2bf(v0.x); p.u[1] = f2bf(v0.y);
            p.u[2] = f2bf(v0.z); p.u[3] = f2bf(v0.w);
            p.u[4] = f2bf(v1.x); p.u[5] = f2bf(v1.y);
            p.u[6] = f2bf(v1.z); p.u[7] = f2bf(v1.w);
            *(shortx8*)&la[row * 32 + ksw(row, a_g)] = p.v;
        }
#pragma unroll
        for (int r = 0; r < 2; ++r) {
            const int g = b_g0 + r * 2;
            const float* src = Bbase + (size_t)(k0 + g * 8) * Np + b_n;
            BfPack p;
#pragma unroll
            for (int u = 0; u < 8; ++u)
                p.u[u] = f2bf(src[(size_t)u * Np]);
            *(shortx8*)&lb[b_n * 32 + ksw(b_n, g)] = p.v;
        }
        __syncthreads();
        shortx8 af[4], bf[4];
#pragma unroll
        for (int i = 0; i < 4; ++i) {
            const int row = wm + i * 16 + lane15;
            af[i] = *(const shortx8*)&la[row * 32 + ksw(row, quad)];
        }
#pragma unroll
        for (int j = 0; j < 4; ++j) {
            const int nn = wn + j * 16 + lane15;
            bf[j] = *(const shortx8*)&lb[nn * 32 + ksw(nn, quad)];
        }
#pragma unroll
        for (int i = 0; i < 4; ++i)
#pragma unroll
            for (int j = 0; j < 4; ++j)
                acc[i][j] = __builtin_amdgcn_mfma_f32_16x16x32_bf16(
                    af[i], bf[j], acc[i][j], 0, 0, 0);
    }

#pragma unroll
    for (int i = 0; i < 4; ++i) {
#pragma unroll
        for (int j = 0; j < 4; ++j) {
#pragma unroll
            for (int reg = 0; reg < 4; ++reg) {
                const int row = bm0 + wm + i * 16 + quad * 4 + reg;
                const int col = bn0 + wn + j * 16 + lane15;
                corr[(size_t)(b * Mq + row) * Np + col] = acc[i][j][reg];
            }
        }
    }
}

// ---------------------------------------------------------------------------
// Fused pyramid + bilinear sampling.
// Block = 8 queries, 256 threads (4 waves; each wave streams 2 queries).
// Streams each query's 64x64 corr image from global ONCE (float4 coalesced),
// builds L1 (32x32) via shfl pair-reduction, captures the 10x10 L0 window,
// derives L2/L3 in LDS, then emits all 324 outputs per query.
// Levels 1..3 are never materialized in HBM.
// ---------------------------------------------------------------------------
__global__ __launch_bounds__(256)
void pyr_sample_kernel(const float* __restrict__ cent,  // (Bb*Mq, 2)
                       const float* __restrict__ corr,  // (Bb*Mq, 64*64)
                       float* __restrict__ out)         // (Bb, 324, Mq)
{
    __shared__ float l1[8][1024];    // 32x32 pooled
    __shared__ float l2[8][256];     // 16x16 pooled
    __shared__ float l3[8][64];      // 8x8 pooled
    __shared__ float win0[8][100];   // 10x10 L0 window
    __shared__ float qcx[8], qcy[8];
    __shared__ int   qx0[8], qy0[8];

    const int tid  = threadIdx.x;
    const int lane = tid & 63;
    const int wave = tid >> 6;
    const int b    = blockIdx.x >> 9;          // Mq/8 = 512 blocks per batch
    const int m0   = (blockIdx.x & 511) * 8;

    // Phase 0: per-query centroid info
    if (tid < 8) {
        const float cx = cent[(size_t)(b * Mq + m0 + tid) * 2 + 0];
        const float cy = cent[(size_t)(b * Mq + m0 + tid) * 2 + 1];
        qcx[tid] = cx; qcy[tid] = cy;
        qx0[tid] = (int)floorf(cx) - RAD;
        qy0[tid] = (int)floorf(cy) - RAD;
    }
    __syncthreads();

    // Phase 1: stream 2 queries per wave; build L1 + capture L0 window.
    // Iteration it covers rows 4*it .. 4*it+3 (64 lanes x float4 = 256 floats).
    const int xb = 4 * (lane & 15);        // lane's first x
    const int rg = lane >> 4;              // row group 0..3
#pragma unroll
    for (int qi = 0; qi < 2; ++qi) {
        const int q = wave * 2 + qi;
        const float* src = corr + (size_t)(b * Mq + m0 + q) * Np;
        const int x0w = qx0[q], y0w = qy0[q];
#pragma unroll
        for (int it = 0; it < 16; ++it) {
            const float4 v = *(const float4*)(src + it * 256 + lane * 4);
            const int row = 4 * it + rg;
            // L1 partial: horizontal pair sums, then vertical via shfl
            float s0 = v.x + v.y;
            float s1 = v.z + v.w;
            s0 += __shfl_xor(s0, 16, 64);
            s1 += __shfl_xor(s1, 16, 64);
            if ((rg & 1) == 0) {
                const int r1 = row >> 1;
                const int c1 = 2 * (lane & 15);
                l1[q][r1 * 32 + c1]     = 0.25f * s0;
                l1[q][r1 * 32 + c1 + 1] = 0.25f * s1;
            }
            // L0 window capture (rows rarely in range -> cheap)
            const int wy = row - y0w;
            if (wy >= 0 && wy < 10) {
                const float va[4] = {v.x, v.y, v.z, v.w};
#pragma unroll
                for (int u = 0; u < 4; ++u) {
                    const int wx = xb + u - x0w;
                    if (wx >= 0 && wx < 10) win0[q][wy * 10 + wx] = va[u];
                }
            }
        }
    }
    __syncthreads();

    // Phase 2a: L2 from L1 (8 queries x 256 cells = 2048, 8 per thread)
#pragma unroll
    for (int i = 0; i < 8; ++i) {
        const int idx = i * 256 + tid;
        const int q = idx >> 8;
        const int c = idx & 255;
        const int cy2 = c >> 4, cx2 = c & 15;
        const float* s = &l1[q][(2 * cy2) * 32 + 2 * cx2];
        l2[q][c] = 0.25f * (s[0] + s[1] + s[32] + s[33]);
    }
    __syncthreads();

    // Phase 2b: L3 from L2 (8 x 64 = 512, 2 per thread)
#pragma unroll
    for (int i = 0; i < 2; ++i) {
        const int idx = i * 256 + tid;
        const int q = idx >> 6;
        const int c = idx & 63;
        const int cy3 = c >> 3, cx3 = c & 7;
        const float* s = &l2[q][(2 * cy3) * 16 + 2 * cx3];
        l3[q][c] = 0.25f * (s[0] + s[1] + s[16] + s[17]);
    }
    __syncthreads();

    // Phase 3: sampling. 324*8 = 2592 outputs, 11 iterations.
    for (int i = 0; i < 11; ++i) {
        const int idx = i * 256 + tid;
        if (idx >= KTOT * 8) break;
        const int q  = idx & 7;
        const int kk = idx >> 3;           // 0..323
        const int lvl = kk / KPL;
        const int r   = kk - lvl * KPL;
        const int di  = r / SIDE;          // x-offset index
        const int dj  = r - di * SIDE;     // y-offset index

        const int w = Ww >> lvl;
        const float scale = 1.0f / (float)(1 << lvl);
        const float x = qcx[q] * scale + (float)(di - RAD);
        const float y = qcy[q] * scale + (float)(dj - RAD);

        const float x0f = floorf(x), y0f = floorf(y);
        const float wx1 = x - x0f, wx0 = 1.0f - wx1;
        const float wy1 = y - y0f, wy0 = 1.0f - wy1;
        const float fmx = (float)(w - 1);
        const bool vx0 = (x0f >= 0.0f) && (x0f <= fmx);
        const bool vx1 = (x0f + 1.0f >= 0.0f) && (x0f + 1.0f <= fmx);
        const bool vy0 = (y0f >= 0.0f) && (y0f <= fmx);
        const bool vy1 = (y0f + 1.0f >= 0.0f) && (y0f + 1.0f <= fmx);

        const int ix0 = (int)x0f, iy0 = (int)y0f;

        const float* buf;
        int stride, ox, oy;
        if (lvl == 0)      { buf = win0[q]; stride = 10; ox = qx0[q]; oy = qy0[q]; }
        else if (lvl == 1) { buf = l1[q];   stride = 32; ox = 0; oy = 0; }
        else if (lvl == 2) { buf = l2[q];   stride = 16; ox = 0; oy = 0; }
        else               { buf = l3[q];   stride =  8; ox = 0; oy = 0; }

        const int cx0 = ix0 - ox, cx1 = ix0 + 1 - ox;
        const int cy0r = iy0 - oy, cy1r = iy0 + 1 - oy;
        const float g00 = (vx0 && vy0) ? buf[cy0r * stride + cx0] : 0.0f;
        const float g10 = (vx1 && vy0) ? buf[cy0r * stride + cx1] : 0.0f;
        const float g01 = (vx0 && vy1) ? buf[cy1r * stride + cx0] : 0.0f;
        const float g11 = (vx1 && vy1) ? buf[cy1r * stride + cx1] : 0.0f;

        out[((size_t)b * KTOT + kk) * Mq + m0 + q] =
            wy0 * (wx0 * g00 + wx1 * g10) + wy1 * (wx0 * g01 + wx1 * g11);
    }
}

extern "C" void kernel_launch(void* const* d_in, const int* in_sizes, int n_in,
                              void* d_out, int out_size, void* d_ws, size_t ws_size,
                              hipStream_t stream)
{
    const float* fmap1 = (const float*)d_in[0];   // (Bb, Mq, Cc)
    const float* fmap2 = (const float*)d_in[1];   // (Bb, Cc, Hh, Ww)
    const float* cent  = (const float*)d_in[2];   // (Bb, Mq, 2)
    float* corr = (float*)d_ws;                   // 128 MB level-0 volume
    float* out  = (float*)d_out;

    // 1) correlation volume (level 0)
    dim3 ggrid(Np / 128, Mq / 128, Bb);
    corr_gemm_kernel<<<ggrid, 256, 0, stream>>>(fmap1, fmap2, corr);

    // 2) fused pyramid + sampling (levels 1..3 live only in LDS)
    const int nblk = Bb * Mq / 8;   // 1024
    pyr_sample_kernel<<<nblk, 256, 0, stream>>>(cent, corr, out);
}

// Round 3
// 128.959 us; speedup vs baseline: 1.3813x; 1.1264x over previous
//
#include <hip/hip_runtime.h>
#include <stdint.h>
#include <stddef.h>

// Problem constants (match reference setup_inputs)
static constexpr int Bb = 2;      // batch
static constexpr int Mq = 4096;   // queries per batch
static constexpr int Cc = 256;    // channels (GEMM K)
static constexpr int Hh = 64, Ww = 64;
static constexpr int Np = Hh * Ww;     // 4096 pixels (GEMM N)
static constexpr int RAD = 4;
static constexpr int SIDE = 2 * RAD + 1;     // 9
static constexpr int KPL = SIDE * SIDE;      // 81
static constexpr int NLVL = 4;
static constexpr int KTOT = NLVL * KPL;      // 324

// Workspace layout (floats):
//   l1buf : (Bb*Mq) x 32*32   pooled level-1            = 33.5 MB
//   winbuf: (Bb*Mq) x 100     10x10 level-0 windows     =  3.3 MB
static constexpr size_t L1BUF_OFF  = 0;
static constexpr size_t WINBUF_OFF = (size_t)Bb * Mq * 1024;

typedef float floatx4 __attribute__((ext_vector_type(4)));
typedef short shortx8 __attribute__((ext_vector_type(8)));

union BfPack {
    shortx8 v;
    unsigned short u[8];
};

// fp32 -> bf16 round-to-nearest-even (finite inputs only)
__device__ __forceinline__ unsigned short f2bf(float f) {
    unsigned int x = __float_as_uint(f);
    x += 0x7fffu + ((x >> 16) & 1u);
    return (unsigned short)(x >> 16);
}

// XOR swizzle of the k-group (8 bf16 = 16B) within a 32-elem LDS row
__device__ __forceinline__ int ksw(int row, int g) {
    return 8 * (g ^ ((row >> 1) & 3));
}

// ---------------------------------------------------------------------------
// Fused correlation GEMM + level-1 pooling + level-0 window extraction.
// corr[b*Mq+m][p] = sum_c fmap1[b][m][c] * fmap2[b][c][p]
// 128x128 tile per block, BK=32, bf16 MFMA 16x16x32, 4 waves, 4x4 tiles/wave.
// N-tile 128 = image rows {2*bx, 2*bx+1} -> epilogue pools 2x2 into one L1
// row per query and scatters the rows intersecting each query's 10x10
// sampling window. The 128 MB corr volume never touches HBM.
// ---------------------------------------------------------------------------
__global__ __launch_bounds__(256)
void corr_gemm_pool_kernel(const float* __restrict__ A,    // (Bb*Mq, Cc)
                           const float* __restrict__ B2,   // (Bb, Cc, Np)
                           const float* __restrict__ cent, // (Bb*Mq, 2)
                           float* __restrict__ l1buf,      // (Bb*Mq, 1024)
                           float* __restrict__ winbuf)     // (Bb*Mq, 100)
{
    __shared__ unsigned short la[128 * 32];  // A tile, row-major [m][k]
    __shared__ unsigned short lb[128 * 32];  // B tile, n-major  [n][k]
    __shared__ float corrT[32 * 129];        // chunk staging, pad->conflict-free
    __shared__ int   qx0s[128], qy0s[128];

    const int b    = blockIdx.z;
    const int bm0  = blockIdx.y * 128;
    const int bx   = blockIdx.x;             // image row pair {2bx, 2bx+1}
    const int bn0  = bx * 128;
    const int tid  = threadIdx.x;
    const int lane = tid & 63;
    const int wave = tid >> 6;
    const int lane15 = lane & 15;
    const int quad   = lane >> 4;
    const int wm = (wave >> 1) * 64;
    const int wn = (wave & 1) * 64;

    // centroid-derived window origins for this block's 128 queries
    if (tid < 128) {
        const float cx = cent[(size_t)(b * Mq + bm0 + tid) * 2 + 0];
        const float cy = cent[(size_t)(b * Mq + bm0 + tid) * 2 + 1];
        qx0s[tid] = (int)floorf(cx) - RAD;
        qy0s[tid] = (int)floorf(cy) - RAD;
    }

    const float* Abase = A + (size_t)(b * Mq + bm0) * Cc;
    const float* Bbase = B2 + (size_t)b * Cc * Np + bn0;

    floatx4 acc[4][4];
#pragma unroll
    for (int i = 0; i < 4; ++i)
#pragma unroll
        for (int j = 0; j < 4; ++j)
            acc[i][j] = floatx4{0.0f, 0.0f, 0.0f, 0.0f};

    const int a_row = tid >> 2;   // 0..63 (round adds 64)
    const int a_g   = tid & 3;    // k-group 0..3
    const int b_n   = tid & 127;  // 0..127
    const int b_g0  = tid >> 7;   // 0..1 (round adds 2)

    for (int k0 = 0; k0 < Cc; k0 += 32) {
        __syncthreads();
#pragma unroll
        for (int r = 0; r < 2; ++r) {
            const int row = a_row + r * 64;
            const float* src = Abase + (size_t)row * Cc + k0 + a_g * 8;
            const float4 v0 = *(const float4*)(src);
            const float4 v1 = *(const float4*)(src + 4);
            BfPack p;
            p.u[0] = f2bf(v0.x); p.u[1] = f2bf(v0.y);
            p.u[2] = f2bf(v0.z); p.u[3] = f2bf(v0.w);
            p.u[4] = f2bf(v1.x); p.u[5] = f2bf(v1.y);
            p.u[6] = f2bf(v1.z); p.u[7] = f2bf(v1.w);
            *(shortx8*)&la[row * 32 + ksw(row, a_g)] = p.v;
        }
#pragma unroll
        for (int r = 0; r < 2; ++r) {
            const int g = b_g0 + r * 2;
            const float* src = Bbase + (size_t)(k0 + g * 8) * Np + b_n;
            BfPack p;
#pragma unroll
            for (int u = 0; u < 8; ++u)
                p.u[u] = f2bf(src[(size_t)u * Np]);
            *(shortx8*)&lb[b_n * 32 + ksw(b_n, g)] = p.v;
        }
        __syncthreads();
        shortx8 af[4], bf[4];
#pragma unroll
        for (int i = 0; i < 4; ++i) {
            const int row = wm + i * 16 + lane15;
            af[i] = *(const shortx8*)&la[row * 32 + ksw(row, quad)];
        }
#pragma unroll
        for (int j = 0; j < 4; ++j) {
            const int nn = wn + j * 16 + lane15;
            bf[j] = *(const shortx8*)&lb[nn * 32 + ksw(nn, quad)];
        }
#pragma unroll
        for (int i = 0; i < 4; ++i)
#pragma unroll
            for (int j = 0; j < 4; ++j)
                acc[i][j] = __builtin_amdgcn_mfma_f32_16x16x32_bf16(
                    af[i], bf[j], acc[i][j], 0, 0, 0);
    }

    // ---- epilogue: 4 chunks of 32 queries through LDS; pool + window ----
    // C/D layout: col = lane15, row = quad*4+reg (m89/m91 verified).
    // corrT row r_local (query in chunk), col n: n<64 -> y=2bx, n>=64 -> y=2bx+1.
    const int m_local = tid >> 3;   // 0..31 (query within chunk)
    const int xi      = tid & 7;
#pragma unroll
    for (int c = 0; c < 4; ++c) {
        __syncthreads();
        if ((wave >> 1) == (c >> 1)) {
#pragma unroll
            for (int ii = 0; ii < 2; ++ii) {
                const int i = 2 * (c & 1) + ii;
#pragma unroll
                for (int j = 0; j < 4; ++j) {
#pragma unroll
                    for (int reg = 0; reg < 4; ++reg) {
                        const int rl = ii * 16 + quad * 4 + reg;
                        const int n  = wn + j * 16 + lane15;
                        corrT[rl * 129 + n] = acc[i][j][reg];
                    }
                }
            }
        }
        __syncthreads();

        const int mg = 32 * c + m_local;            // block-local query
        const size_t gq = (size_t)(b * Mq + bm0 + mg);
        const float* T = &corrT[m_local * 129];

        // 2x2 pool -> one L1 row (32 values) per query
#pragma unroll
        for (int k = 0; k < 4; ++k) {
            const int c1 = xi + 8 * k;
            const float v = 0.25f * (T[2 * c1] + T[2 * c1 + 1]
                                   + T[64 + 2 * c1] + T[64 + 2 * c1 + 1]);
            l1buf[gq * 1024 + bx * 32 + c1] = v;
        }

        // level-0 window rows intersecting [qy0, qy0+9]
        const int x0w = qx0s[mg];
        const int y0w = qy0s[mg];
#pragma unroll
        for (int par = 0; par < 2; ++par) {
            const int wy = 2 * bx + par - y0w;
            if (wy >= 0 && wy < 10) {
#pragma unroll
                for (int t = 0; t < 2; ++t) {
                    const int wx = xi + t * 8;
                    if (wx < 10) {
                        const int x = x0w + wx;
                        if (x >= 0 && x < Ww)
                            winbuf[gq * 100 + wy * 10 + wx] = T[par * 64 + x];
                    }
                }
            }
        }
    }
}

// ---------------------------------------------------------------------------
// Sampler: 8 queries/block. Loads L1 (4 KB/query) + window (400 B/query),
// builds L2/L3 in LDS, emits all 324 outputs per query.
// ---------------------------------------------------------------------------
__global__ __launch_bounds__(256)
void pyr_sample_kernel(const float* __restrict__ cent,   // (Bb*Mq, 2)
                       const float* __restrict__ l1buf,  // (Bb*Mq, 1024)
                       const float* __restrict__ winbuf, // (Bb*Mq, 100)
                       float* __restrict__ out)          // (Bb, 324, Mq)
{
    __shared__ float l1[8][1024];    // 32x32
    __shared__ float l2[8][256];     // 16x16
    __shared__ float l3[8][64];      // 8x8
    __shared__ float win0[8][100];   // 10x10 L0 window
    __shared__ float qcx[8], qcy[8];
    __shared__ int   qx0[8], qy0[8];

    const int tid = threadIdx.x;
    const int b   = blockIdx.x >> 9;           // 512 blocks per batch
    const int m0  = (blockIdx.x & 511) * 8;
    const size_t gq0 = (size_t)(b * Mq + m0);

    if (tid < 8) {
        const float cx = cent[(gq0 + tid) * 2 + 0];
        const float cy = cent[(gq0 + tid) * 2 + 1];
        qcx[tid] = cx; qcy[tid] = cy;
        qx0[tid] = (int)floorf(cx) - RAD;
        qy0[tid] = (int)floorf(cy) - RAD;
    }

    // load L1: 8 queries x 256 float4
#pragma unroll
    for (int it = 0; it < 8; ++it) {
        const int v = it * 256 + tid;          // float4 index
        const int q = v >> 8;
        const int o = v & 255;
        *(float4*)&l1[q][o * 4] = *(const float4*)&l1buf[(gq0 + q) * 1024 + o * 4];
    }
    // load windows: 8 queries x 25 float4
    if (tid < 200) {
        const int q = tid / 25;
        const int o = tid - q * 25;
        *(float4*)&win0[q][o * 4] = *(const float4*)&winbuf[(gq0 + q) * 100 + o * 4];
    }
    __syncthreads();

    // L2 from L1
#pragma unroll
    for (int i = 0; i < 8; ++i) {
        const int idx = i * 256 + tid;
        const int q = idx >> 8;
        const int c = idx & 255;
        const int cy2 = c >> 4, cx2 = c & 15;
        const float* s = &l1[q][(2 * cy2) * 32 + 2 * cx2];
        l2[q][c] = 0.25f * (s[0] + s[1] + s[32] + s[33]);
    }
    __syncthreads();
    // L3 from L2
#pragma unroll
    for (int i = 0; i < 2; ++i) {
        const int idx = i * 256 + tid;
        const int q = idx >> 6;
        const int c = idx & 63;
        const int cy3 = c >> 3, cx3 = c & 7;
        const float* s = &l2[q][(2 * cy3) * 16 + 2 * cx3];
        l3[q][c] = 0.25f * (s[0] + s[1] + s[16] + s[17]);
    }
    __syncthreads();

    // sampling: 324*8 = 2592 outputs
    for (int i = 0; i < 11; ++i) {
        const int idx = i * 256 + tid;
        if (idx >= KTOT * 8) break;
        const int q  = idx & 7;
        const int kk = idx >> 3;           // 0..323
        const int lvl = kk / KPL;
        const int r   = kk - lvl * KPL;
        const int di  = r / SIDE;          // x-offset index
        const int dj  = r - di * SIDE;     // y-offset index

        const int w = Ww >> lvl;
        const float scale = 1.0f / (float)(1 << lvl);
        const float x = qcx[q] * scale + (float)(di - RAD);
        const float y = qcy[q] * scale + (float)(dj - RAD);

        const float x0f = floorf(x), y0f = floorf(y);
        const float wx1 = x - x0f, wx0 = 1.0f - wx1;
        const float wy1 = y - y0f, wy0 = 1.0f - wy1;
        const float fmx = (float)(w - 1);
        const bool vx0 = (x0f >= 0.0f) && (x0f <= fmx);
        const bool vx1 = (x0f + 1.0f >= 0.0f) && (x0f + 1.0f <= fmx);
        const bool vy0 = (y0f >= 0.0f) && (y0f <= fmx);
        const bool vy1 = (y0f + 1.0f >= 0.0f) && (y0f + 1.0f <= fmx);

        const int ix0 = (int)x0f, iy0 = (int)y0f;

        const float* buf;
        int stride, ox, oy;
        if (lvl == 0)      { buf = win0[q]; stride = 10; ox = qx0[q]; oy = qy0[q]; }
        else if (lvl == 1) { buf = l1[q];   stride = 32; ox = 0; oy = 0; }
        else if (lvl == 2) { buf = l2[q];   stride = 16; ox = 0; oy = 0; }
        else               { buf = l3[q];   stride =  8; ox = 0; oy = 0; }

        const int cx0 = ix0 - ox, cx1 = ix0 + 1 - ox;
        const int cy0r = iy0 - oy, cy1r = iy0 + 1 - oy;
        const float g00 = (vx0 && vy0) ? buf[cy0r * stride + cx0] : 0.0f;
        const float g10 = (vx1 && vy0) ? buf[cy0r * stride + cx1] : 0.0f;
        const float g01 = (vx0 && vy1) ? buf[cy1r * stride + cx0] : 0.0f;
        const float g11 = (vx1 && vy1) ? buf[cy1r * stride + cx1] : 0.0f;

        out[((size_t)b * KTOT + kk) * Mq + m0 + q] =
            wy0 * (wx0 * g00 + wx1 * g10) + wy1 * (wx0 * g01 + wx1 * g11);
    }
}

extern "C" void kernel_launch(void* const* d_in, const int* in_sizes, int n_in,
                              void* d_out, int out_size, void* d_ws, size_t ws_size,
                              hipStream_t stream)
{
    const float* fmap1 = (const float*)d_in[0];   // (Bb, Mq, Cc)
    const float* fmap2 = (const float*)d_in[1];   // (Bb, Cc, Hh, Ww)
    const float* cent  = (const float*)d_in[2];   // (Bb, Mq, 2)
    float* l1buf  = (float*)d_ws + L1BUF_OFF;
    float* winbuf = (float*)d_ws + WINBUF_OFF;
    float* out = (float*)d_out;

    // 1) fused correlation GEMM + L1 pooling + L0 window extraction
    dim3 ggrid(Np / 128, Mq / 128, Bb);
    corr_gemm_pool_kernel<<<ggrid, 256, 0, stream>>>(fmap1, fmap2, cent,
                                                     l1buf, winbuf);

    // 2) pyramid completion (L2/L3 in LDS) + bilinear sampling
    const int nblk = Bb * Mq / 8;   // 1024
    pyr_sample_kernel<<<nblk, 256, 0, stream>>>(cent, l1buf, winbuf, out);
}

// Round 4
// 128.727 us; speedup vs baseline: 1.3838x; 1.0018x over previous
//
#include <hip/hip_runtime.h>
#include <stdint.h>
#include <stddef.h>

// Problem constants (match reference setup_inputs)
static constexpr int Bb = 2;      // batch
static constexpr int Mq = 4096;   // queries per batch
static constexpr int Cc = 256;    // channels (GEMM K)
static constexpr int Hh = 64, Ww = 64;
static constexpr int Np = Hh * Ww;     // 4096 pixels (GEMM N)
static constexpr int RAD = 4;
static constexpr int SIDE = 2 * RAD + 1;     // 9
static constexpr int KPL = SIDE * SIDE;      // 81
static constexpr int NLVL = 4;
static constexpr int KTOT = NLVL * KPL;      // 324

// Workspace layout (bytes)
static constexpr size_t L1BUF_B  = 0;                                   // 33.5 MB fp32
static constexpr size_t WINBUF_B = (size_t)Bb * Mq * 1024 * 4;          // +3.3 MB fp32
static constexpr size_t ABF_B    = WINBUF_B + (size_t)Bb * Mq * 100 * 4;// +4.2 MB bf16
static constexpr size_t BT_B     = ABF_B + (size_t)Bb * Mq * Cc * 2;    // +4.2 MB bf16

typedef float floatx4 __attribute__((ext_vector_type(4)));
typedef short shortx8 __attribute__((ext_vector_type(8)));

union BfPack {
    shortx8 v;
    unsigned short u[8];
};

// fp32 -> bf16 round-to-nearest-even (finite inputs only)
__device__ __forceinline__ unsigned short f2bf(float f) {
    unsigned int x = __float_as_uint(f);
    x += 0x7fffu + ((x >> 16) & 1u);
    return (unsigned short)(x >> 16);
}

// async global->LDS, 16 B per lane; LDS dest = base + lane*16 (wave-uniform base)
__device__ __forceinline__ void gll16(const void* g, void* l) {
    __builtin_amdgcn_global_load_lds(
        (const __attribute__((address_space(1))) unsigned int*)g,
        (__attribute__((address_space(3))) unsigned int*)l, 16, 0, 0);
}

// ---------------------------------------------------------------------------
// fmap1 fp32 -> bf16, same layout. 8 elements/thread.
// ---------------------------------------------------------------------------
__global__ __launch_bounds__(256)
void cvt_a_kernel(const float* __restrict__ in, unsigned short* __restrict__ out)
{
    const int t = blockIdx.x * blockDim.x + threadIdx.x;   // 262144 threads
    const float4 v0 = *(const float4*)(in + (size_t)t * 8);
    const float4 v1 = *(const float4*)(in + (size_t)t * 8 + 4);
    BfPack p;
    p.u[0] = f2bf(v0.x); p.u[1] = f2bf(v0.y);
    p.u[2] = f2bf(v0.z); p.u[3] = f2bf(v0.w);
    p.u[4] = f2bf(v1.x); p.u[5] = f2bf(v1.y);
    p.u[6] = f2bf(v1.z); p.u[7] = f2bf(v1.w);
    *(shortx8*)(out + (size_t)t * 8) = p.v;
}

// ---------------------------------------------------------------------------
// fmap2 (b, c, p) fp32 -> Bt (b, p, c) bf16 via 64x64 LDS tile transpose.
// ---------------------------------------------------------------------------
__global__ __launch_bounds__(256)
void cvt_bt_kernel(const float* __restrict__ in, unsigned short* __restrict__ out)
{
    __shared__ float tile[64 * 65];
    const int p0 = blockIdx.x * 64;
    const int c0 = blockIdx.y * 64;
    const int b  = blockIdx.z;
    const int tid = threadIdx.x;

    // load: coalesced along p
    const int pl = tid & 63;
    const int cb = tid >> 6;     // 0..3
#pragma unroll
    for (int it = 0; it < 16; ++it) {
        const int cl = it * 4 + cb;
        tile[cl * 65 + pl] = in[((size_t)(b * Cc + c0 + cl)) * Np + p0 + pl];
    }
    __syncthreads();

    // store: coalesced along c (8 bf16 = 16 B per thread-write)
    const int cg = (tid & 7) * 8;
#pragma unroll
    for (int it = 0; it < 2; ++it) {
        const int pw = it * 32 + (tid >> 3);
        BfPack p;
#pragma unroll
        for (int u = 0; u < 8; ++u)
            p.u[u] = f2bf(tile[(cg + u) * 65 + pw]);
        *(shortx8*)(out + ((size_t)(b * Np + p0 + pw)) * Cc + c0 + cg) = p.v;
    }
}

// ---------------------------------------------------------------------------
// Fused correlation GEMM + level-1 pooling + level-0 window extraction.
// m97-style staging: both operands bf16 k-contiguous, global_load_lds w=16.
// 128x128 tile, BK=32, mfma_f32_16x16x32_bf16, 4 waves, 4x4 tiles/wave.
// LDS union: la/lb (K-loop) reused as corrT (epilogue) -> 17.6 KB total.
// ---------------------------------------------------------------------------
__global__ __launch_bounds__(256)
void corr_gemm_pool_kernel(const unsigned short* __restrict__ Abf, // (Bb*Mq, Cc)
                           const unsigned short* __restrict__ Bt,  // (Bb*Np, Cc)
                           const float* __restrict__ cent,         // (Bb*Mq, 2)
                           float* __restrict__ l1buf,              // (Bb*Mq, 1024)
                           float* __restrict__ winbuf)             // (Bb*Mq, 100)
{
    __shared__ union {
        struct { unsigned short la[128 * 32]; unsigned short lb[128 * 32]; } t;
        float corrT[32 * 130];   // stride 130 -> 2-way (free) epilogue banking
    } sm;
    __shared__ int qx0s[128], qy0s[128];

    const int b    = blockIdx.z;
    const int bm0  = blockIdx.y * 128;
    const int bx   = blockIdx.x;             // image row pair {2bx, 2bx+1}
    const int bn0  = bx * 128;
    const int tid  = threadIdx.x;
    const int lane = tid & 63;
    const int wave = tid >> 6;
    const int lane15 = lane & 15;
    const int quad   = lane >> 4;
    const int wm = (wave >> 1) * 64;
    const int wn = (wave & 1) * 64;

    if (tid < 128) {
        const float cx = cent[(size_t)(b * Mq + bm0 + tid) * 2 + 0];
        const float cy = cent[(size_t)(b * Mq + bm0 + tid) * 2 + 1];
        qx0s[tid] = (int)floorf(cx) - RAD;
        qy0s[tid] = (int)floorf(cy) - RAD;
    }

    unsigned short* la = sm.t.la;
    unsigned short* lb = sm.t.lb;

    // staging addresses: instr covers 16 rows; lane -> row lane/4, kgroup lane%4
    const int lrow = lane >> 2;
    const int lkg  = (lane & 3) * 8;
    const unsigned short* aptr = Abf + (size_t)(b * Mq + bm0 + wave * 16 + lrow) * Cc + lkg;
    const unsigned short* bptr = Bt  + (size_t)(b * Np + bn0 + wave * 16 + lrow) * Cc + lkg;

    floatx4 acc[4][4];
#pragma unroll
    for (int i = 0; i < 4; ++i)
#pragma unroll
        for (int j = 0; j < 4; ++j)
            acc[i][j] = floatx4{0.0f, 0.0f, 0.0f, 0.0f};

    for (int k0 = 0; k0 < Cc; k0 += 32) {
        __syncthreads();
        gll16(aptr + k0,            &la[wave * 512]);
        gll16(aptr + 64 * Cc + k0,  &la[2048 + wave * 512]);
        gll16(bptr + k0,            &lb[wave * 512]);
        gll16(bptr + 64 * Cc + k0,  &lb[2048 + wave * 512]);
        __syncthreads();   // drains vmcnt (compiler emits waitcnt before barrier)

        shortx8 af[4], bf[4];
#pragma unroll
        for (int i = 0; i < 4; ++i)
            af[i] = *(const shortx8*)&la[(wm + i * 16 + lane15) * 32 + quad * 8];
#pragma unroll
        for (int j = 0; j < 4; ++j)
            bf[j] = *(const shortx8*)&lb[(wn + j * 16 + lane15) * 32 + quad * 8];
#pragma unroll
        for (int i = 0; i < 4; ++i)
#pragma unroll
            for (int j = 0; j < 4; ++j)
                acc[i][j] = __builtin_amdgcn_mfma_f32_16x16x32_bf16(
                    af[i], bf[j], acc[i][j], 0, 0, 0);
    }

    // ---- epilogue: 4 chunks of 32 queries through LDS; pool + window ----
    // C/D layout: col = lane15, row = quad*4+reg (m89/m91 verified).
    float* corrT = sm.corrT;
    const int m_local = tid >> 3;   // 0..31 (query within chunk)
    const int xi      = tid & 7;
#pragma unroll
    for (int c = 0; c < 4; ++c) {
        __syncthreads();
        if ((wave >> 1) == (c >> 1)) {
#pragma unroll
            for (int ii = 0; ii < 2; ++ii) {
                const int i = 2 * (c & 1) + ii;
#pragma unroll
                for (int j = 0; j < 4; ++j) {
#pragma unroll
                    for (int reg = 0; reg < 4; ++reg) {
                        const int rl = ii * 16 + quad * 4 + reg;
                        const int n  = wn + j * 16 + lane15;
                        corrT[rl * 130 + n] = acc[i][j][reg];
                    }
                }
            }
        }
        __syncthreads();

        const int mg = 32 * c + m_local;            // block-local query
        const size_t gq = (size_t)(b * Mq + bm0 + mg);
        const float* T = &corrT[m_local * 130];

        // 2x2 pool -> one L1 row (32 values) per query
#pragma unroll
        for (int k = 0; k < 4; ++k) {
            const int c1 = xi + 8 * k;
            const float v = 0.25f * (T[2 * c1] + T[2 * c1 + 1]
                                   + T[64 + 2 * c1] + T[64 + 2 * c1 + 1]);
            l1buf[gq * 1024 + bx * 32 + c1] = v;
        }

        // level-0 window rows intersecting [qy0, qy0+9]
        const int x0w = qx0s[mg];
        const int y0w = qy0s[mg];
#pragma unroll
        for (int par = 0; par < 2; ++par) {
            const int wy = 2 * bx + par - y0w;
            if (wy >= 0 && wy < 10) {
#pragma unroll
                for (int t = 0; t < 2; ++t) {
                    const int wx = xi + t * 8;
                    if (wx < 10) {
                        const int x = x0w + wx;
                        if (x >= 0 && x < Ww)
                            winbuf[gq * 100 + wy * 10 + wx] = T[par * 64 + x];
                    }
                }
            }
        }
    }
}

// ---------------------------------------------------------------------------
// Sampler: 8 queries/block. Loads L1 (4 KB/query) + window (400 B/query),
// builds L2/L3 in LDS, emits all 324 outputs per query.
// ---------------------------------------------------------------------------
__global__ __launch_bounds__(256)
void pyr_sample_kernel(const float* __restrict__ cent,   // (Bb*Mq, 2)
                       const float* __restrict__ l1buf,  // (Bb*Mq, 1024)
                       const float* __restrict__ winbuf, // (Bb*Mq, 100)
                       float* __restrict__ out)          // (Bb, 324, Mq)
{
    __shared__ float l1[8][1024];    // 32x32
    __shared__ float l2[8][256];     // 16x16
    __shared__ float l3[8][64];      // 8x8
    __shared__ float win0[8][100];   // 10x10 L0 window
    __shared__ float qcx[8], qcy[8];
    __shared__ int   qx0[8], qy0[8];

    const int tid = threadIdx.x;
    const int b   = blockIdx.x >> 9;           // 512 blocks per batch
    const int m0  = (blockIdx.x & 511) * 8;
    const size_t gq0 = (size_t)(b * Mq + m0);

    if (tid < 8) {
        const float cx = cent[(gq0 + tid) * 2 + 0];
        const float cy = cent[(gq0 + tid) * 2 + 1];
        qcx[tid] = cx; qcy[tid] = cy;
        qx0[tid] = (int)floorf(cx) - RAD;
        qy0[tid] = (int)floorf(cy) - RAD;
    }

    // load L1: 8 queries x 256 float4
#pragma unroll
    for (int it = 0; it < 8; ++it) {
        const int v = it * 256 + tid;          // float4 index
        const int q = v >> 8;
        const int o = v & 255;
        *(float4*)&l1[q][o * 4] = *(const float4*)&l1buf[(gq0 + q) * 1024 + o * 4];
    }
    // load windows: 8 queries x 25 float4
    if (tid < 200) {
        const int q = tid / 25;
        const int o = tid - q * 25;
        *(float4*)&win0[q][o * 4] = *(const float4*)&winbuf[(gq0 + q) * 100 + o * 4];
    }
    __syncthreads();

    // L2 from L1
#pragma unroll
    for (int i = 0; i < 8; ++i) {
        const int idx = i * 256 + tid;
        const int q = idx >> 8;
        const int c = idx & 255;
        const int cy2 = c >> 4, cx2 = c & 15;
        const float* s = &l1[q][(2 * cy2) * 32 + 2 * cx2];
        l2[q][c] = 0.25f * (s[0] + s[1] + s[32] + s[33]);
    }
    __syncthreads();
    // L3 from L2
#pragma unroll
    for (int i = 0; i < 2; ++i) {
        const int idx = i * 256 + tid;
        const int q = idx >> 6;
        const int c = idx & 63;
        const int cy3 = c >> 3, cx3 = c & 7;
        const float* s = &l2[q][(2 * cy3) * 16 + 2 * cx3];
        l3[q][c] = 0.25f * (s[0] + s[1] + s[16] + s[17]);
    }
    __syncthreads();

    // sampling: 324*8 = 2592 outputs
    for (int i = 0; i < 11; ++i) {
        const int idx = i * 256 + tid;
        if (idx >= KTOT * 8) break;
        const int q  = idx & 7;
        const int kk = idx >> 3;           // 0..323
        const int lvl = kk / KPL;
        const int r   = kk - lvl * KPL;
        const int di  = r / SIDE;          // x-offset index
        const int dj  = r - di * SIDE;     // y-offset index

        const int w = Ww >> lvl;
        const float scale = 1.0f / (float)(1 << lvl);
        const float x = qcx[q] * scale + (float)(di - RAD);
        const float y = qcy[q] * scale + (float)(dj - RAD);

        const float x0f = floorf(x), y0f = floorf(y);
        const float wx1 = x - x0f, wx0 = 1.0f - wx1;
        const float wy1 = y - y0f, wy0 = 1.0f - wy1;
        const float fmx = (float)(w - 1);
        const bool vx0 = (x0f >= 0.0f) && (x0f <= fmx);
        const bool vx1 = (x0f + 1.0f >= 0.0f) && (x0f + 1.0f <= fmx);
        const bool vy0 = (y0f >= 0.0f) && (y0f <= fmx);
        const bool vy1 = (y0f + 1.0f >= 0.0f) && (y0f + 1.0f <= fmx);

        const int ix0 = (int)x0f, iy0 = (int)y0f;

        const float* buf;
        int stride, ox, oy;
        if (lvl == 0)      { buf = win0[q]; stride = 10; ox = qx0[q]; oy = qy0[q]; }
        else if (lvl == 1) { buf = l1[q];   stride = 32; ox = 0; oy = 0; }
        else if (lvl == 2) { buf = l2[q];   stride = 16; ox = 0; oy = 0; }
        else               { buf = l3[q];   stride =  8; ox = 0; oy = 0; }

        const int cx0 = ix0 - ox, cx1 = ix0 + 1 - ox;
        const int cy0r = iy0 - oy, cy1r = iy0 + 1 - oy;
        const float g00 = (vx0 && vy0) ? buf[cy0r * stride + cx0] : 0.0f;
        const float g10 = (vx1 && vy0) ? buf[cy0r * stride + cx1] : 0.0f;
        const float g01 = (vx0 && vy1) ? buf[cy1r * stride + cx0] : 0.0f;
        const float g11 = (vx1 && vy1) ? buf[cy1r * stride + cx1] : 0.0f;

        out[((size_t)b * KTOT + kk) * Mq + m0 + q] =
            wy0 * (wx0 * g00 + wx1 * g10) + wy1 * (wx0 * g01 + wx1 * g11);
    }
}

extern "C" void kernel_launch(void* const* d_in, const int* in_sizes, int n_in,
                              void* d_out, int out_size, void* d_ws, size_t ws_size,
                              hipStream_t stream)
{
    const float* fmap1 = (const float*)d_in[0];   // (Bb, Mq, Cc)
    const float* fmap2 = (const float*)d_in[1];   // (Bb, Cc, Hh, Ww)
    const float* cent  = (const float*)d_in[2];   // (Bb, Mq, 2)
    char* ws = (char*)d_ws;
    float* l1buf  = (float*)(ws + L1BUF_B);
    float* winbuf = (float*)(ws + WINBUF_B);
    unsigned short* Abf = (unsigned short*)(ws + ABF_B);
    unsigned short* Bt  = (unsigned short*)(ws + BT_B);
    float* out = (float*)d_out;

    // 0) dtype conversion / transpose prep
    cvt_a_kernel<<<Bb * Mq * Cc / (8 * 256), 256, 0, stream>>>(fmap1, Abf);
    dim3 tgrid(Np / 64, Cc / 64, Bb);
    cvt_bt_kernel<<<tgrid, 256, 0, stream>>>(fmap2, Bt);

    // 1) fused correlation GEMM + L1 pooling + L0 window extraction
    dim3 ggrid(Np / 128, Mq / 128, Bb);
    corr_gemm_pool_kernel<<<ggrid, 256, 0, stream>>>(Abf, Bt, cent, l1buf, winbuf);

    // 2) pyramid completion (L2/L3 in LDS) + bilinear sampling
    const int nblk = Bb * Mq / 8;   // 1024
    pyr_sample_kernel<<<nblk, 256, 0, stream>>>(cent, l1buf, winbuf, out);
}